// Round 3
// baseline (1233.987 us; speedup 1.0000x reference)
//
#include <hip/hip_runtime.h>

#define N_NODES 1048576
#define THR 16.0f
#define NBLK 1536   // 6 blocks/CU * 256 CU: co-resident by construction (cap is 8/CU)
#define NTHR 256

typedef int int4v __attribute__((ext_vector_type(4)));

// ---- tiny init: zero the two grid-barrier counters and the output scalar ----
// (workspace + d_out are poisoned between calls; stream order makes these
// stores visible to the fused kernel)
__global__ void init_kernel(unsigned* __restrict__ cnt, float* __restrict__ out) {
    cnt[0] = 0u;
    cnt[1] = 0u;
    out[0] = 0.f;
}

// Single-use device-wide barrier. All NBLK blocks are co-resident
// (enforced via __launch_bounds__ + grid size), so spinning is safe.
// Cross-XCD visibility: release fence before arrive, agent-scope atomics
// for the counter, fence after release from the spin.
static __device__ inline void grid_barrier(unsigned* cnt) {
    __syncthreads();
    if (threadIdx.x == 0) {
        __threadfence();   // release: push this block's stores to device scope
        __hip_atomic_fetch_add(cnt, 1u, __ATOMIC_RELEASE, __HIP_MEMORY_SCOPE_AGENT);
        while (__hip_atomic_load(cnt, __ATOMIC_ACQUIRE, __HIP_MEMORY_SCOPE_AGENT) < (unsigned)NBLK) {
            __builtin_amdgcn_s_sleep(2);   // be polite to the fabric while spinning
        }
    }
    __syncthreads();
    __threadfence();       // acquire: discard stale cached lines before reading others' data
}

// cells of width 16: |dx| < 16 is impossible when |cellx_s - cellx_d| >= 2,
// because cx in cell c means cx in [16c, 16c+16), so celldiff k>=2 implies
// |dx| > 16(k-1) >= 16. Prefilter is exactly conservative (no false rejects)
// since cells are computed from the SAME stored cx/cy the exact path gathers.
//
// Persistent fused kernel: phase A (centers+zero) -> barrier -> phase B
// (pair filter + atomic scatter) -> barrier -> phase C (abs-reduce).
__global__ __launch_bounds__(NTHR, 6)
void fused_kernel(const float* __restrict__ pos,
                  const float* __restrict__ nsx,
                  const float* __restrict__ nsy,
                  const int* __restrict__ src,
                  const int* __restrict__ dst,
                  float* __restrict__ cx, float* __restrict__ cy,
                  unsigned short* __restrict__ cell,
                  float* __restrict__ ex, float* __restrict__ ey,
                  unsigned* __restrict__ bar,
                  float* __restrict__ out, int E) {
    const int t = blockIdx.x * NTHR + threadIdx.x;
    const int T = NBLK * NTHR;

    // ---- Phase A: node centers, cell codes, zero force accumulators ----
    for (int i = t; i < N_NODES; i += T) {
        float x = pos[i] + 0.5f * nsx[i];
        float y = pos[N_NODES + i] + 0.5f * nsy[i];
        cx[i] = x;
        cy[i] = y;
        // x,y >= 0 and < ~1026 -> cells 0..64, fits u8 each. *0.0625f exact (pow2).
        int cxi = (int)(x * 0.0625f);
        int cyi = (int)(y * 0.0625f);
        cell[i] = (unsigned short)(cxi | (cyi << 8));
        ex[i] = 0.f;
        ey[i] = 0.f;
    }
    grid_barrier(&bar[0]);

    // ---- Phase B: prefilter via 2 random u16 gathers/pair (service-rate bound) ----
    const int nq = E >> 2;      // quads of pairs; E divisible by 4
    for (int q = t; q < nq; q += T) {
        int base = q << 2;
        // streaming index loads: non-temporal so they don't evict the cell table
        int4v s4 = __builtin_nontemporal_load(reinterpret_cast<const int4v*>(src + base));
        int4v d4 = __builtin_nontemporal_load(reinterpret_cast<const int4v*>(dst + base));
        int ss[4] = {s4.x, s4.y, s4.z, s4.w};
        int dd[4] = {d4.x, d4.y, d4.z, d4.w};
        // issue all 8 cell gathers first (ILP), then evaluate
        int cs[4], cd[4];
#pragma unroll
        for (int k = 0; k < 4; ++k) { cs[k] = cell[ss[k]]; cd[k] = cell[dd[k]]; }
#pragma unroll
        for (int k = 0; k < 4; ++k) {
            int dxc = (cs[k] & 0xff) - (cd[k] & 0xff);
            int dyc = (cs[k] >> 8) - (cd[k] >> 8);
            // pass iff celldiff in {-1,0,1} for both dims (~0.1% of pairs)
            if ((unsigned)(dxc + 1) <= 2u && (unsigned)(dyc + 1) <= 2u) {
                int s = ss[k], d = dd[k];
                float dx = cx[s] - cx[d];
                float dy = cy[s] - cy[d];
                if (fabsf(dx) < THR && fabsf(dy) < THR) {
                    float inv = 0.5f / (dx * dx + dy * dy + 0.01f);
                    float fx = dx * inv;
                    float fy = dy * inv;
                    atomicAdd(&ex[s],  fx);
                    atomicAdd(&ex[d], -fx);
                    atomicAdd(&ey[s],  fy);
                    atomicAdd(&ey[d], -fy);
                }
            }
        }
    }
    grid_barrier(&bar[1]);

    // ---- Phase C: sum |ex| + |ey| (contiguous 2N floats starting at ex) ----
    float sum = 0.f;
    const int n4 = (2 * N_NODES) >> 2;
    const float4* v4 = reinterpret_cast<const float4*>(ex);
    for (int i = t; i < n4; i += T) {
        float4 a = v4[i];
        sum += fabsf(a.x) + fabsf(a.y) + fabsf(a.z) + fabsf(a.w);
    }
#pragma unroll
    for (int off = 32; off > 0; off >>= 1)
        sum += __shfl_down(sum, off, 64);
    __shared__ float ssm[4];
    int wid = threadIdx.x >> 6;
    if ((threadIdx.x & 63) == 0) ssm[wid] = sum;
    __syncthreads();
    if (threadIdx.x == 0)
        atomicAdd(out, ssm[0] + ssm[1] + ssm[2] + ssm[3]);
}

extern "C" void kernel_launch(void* const* d_in, const int* in_sizes, int n_in,
                              void* d_out, int out_size, void* d_ws, size_t ws_size,
                              hipStream_t stream) {
    const float* pos = (const float*)d_in[0];
    const float* nsx = (const float*)d_in[1];
    const float* nsy = (const float*)d_in[2];
    const int*   src = (const int*)d_in[3];
    const int*   dst = (const int*)d_in[4];
    float* out = (float*)d_out;
    int E = in_sizes[3];

    float* cx = (float*)d_ws;                       // [N] f32
    float* cy = cx + N_NODES;                       // [N]
    float* ex = cy + N_NODES;                       // [N]
    float* ey = ex + N_NODES;                       // [N]  (ex,ey contiguous)
    unsigned short* cell = (unsigned short*)(ey + N_NODES);  // [N] u16 = 2MB
    unsigned* bar = (unsigned*)(cell + N_NODES);    // [2] u32 barrier counters

    init_kernel<<<1, 1, 0, stream>>>(bar, out);

    fused_kernel<<<NBLK, NTHR, 0, stream>>>(
        pos, nsx, nsy, src, dst, cx, cy, cell, ex, ey, bar, out, E);
}

// Round 4
// 655.286 us; speedup vs baseline: 1.8831x; 1.8831x over previous
//
#include <hip/hip_runtime.h>

#define N_NODES 1048576
#define THR 16.0f
#define NBLK 1536   // 6 blocks/CU * 256 CU: co-resident by construction (cap is 8/CU)
#define NTHR 256

typedef int int4v __attribute__((ext_vector_type(4)));

// ---- tiny init: zero the two grid-barrier counters and the output scalar ----
// (workspace + d_out are poisoned between calls; stream order makes these
// stores visible to the fused kernel)
__global__ void init_kernel(unsigned* __restrict__ cnt, float* __restrict__ out) {
    cnt[0] = 0u;
    cnt[1] = 0u;
    out[0] = 0.f;
}

// Single-use device-wide barrier with LEADER-ONLY cache maintenance.
// Round-3 lesson: per-thread __threadfence() + per-poll acquire loads emit
// buffer_wbl2/buffer_inv per wave/poll and serialize at the L2 controller
// (1253 us total). Hardware-wise one wbL2 per block (after __syncthreads has
// drained every wave's stores to L2) and one inv per block (before any wave
// issues a post-barrier load) provide the same cross-XCD guarantees:
//   release: syncthreads (vmcnt=0 per wave -> stores in local L2)
//            -> leader __threadfence() (wbL2: flush to coherence point)
//            -> leader release-add on counter (memory-side atomic)
//   acquire: leader relaxed-polls counter (scoped load path, no inv per poll)
//            -> leader __threadfence() (inv L1+L2: drop stale lines)
//            -> syncthreads (no wave loads before leader's inv)
static __device__ inline void grid_barrier(unsigned* cnt) {
    __syncthreads();
    if (threadIdx.x == 0) {
        __threadfence();   // release: one wbL2 per block
        __hip_atomic_fetch_add(cnt, 1u, __ATOMIC_RELEASE, __HIP_MEMORY_SCOPE_AGENT);
        while (__hip_atomic_load(cnt, __ATOMIC_RELAXED, __HIP_MEMORY_SCOPE_AGENT) < (unsigned)NBLK) {
            __builtin_amdgcn_s_sleep(8);   // ~512 cy between polls; no inv per poll
        }
        __threadfence();   // acquire: one inv per block, before any wave's loads
    }
    __syncthreads();
}

// cells of width 16: |dx| < 16 is impossible when |cellx_s - cellx_d| >= 2,
// because cx in cell c means cx in [16c, 16c+16), so celldiff k>=2 implies
// |dx| > 16(k-1) >= 16. Prefilter is exactly conservative (no false rejects)
// since cells are computed from the SAME stored cx/cy the exact path gathers.
//
// Persistent fused kernel: phase A (centers+zero) -> barrier -> phase B
// (pair filter + atomic scatter) -> barrier -> phase C (abs-reduce).
__global__ __launch_bounds__(NTHR, 6)
void fused_kernel(const float* __restrict__ pos,
                  const float* __restrict__ nsx,
                  const float* __restrict__ nsy,
                  const int* __restrict__ src,
                  const int* __restrict__ dst,
                  float* __restrict__ cx, float* __restrict__ cy,
                  unsigned short* __restrict__ cell,
                  float* __restrict__ ex, float* __restrict__ ey,
                  unsigned* __restrict__ bar,
                  float* __restrict__ out, int E) {
    const int t = blockIdx.x * NTHR + threadIdx.x;
    const int T = NBLK * NTHR;

    // ---- Phase A: node centers, cell codes, zero force accumulators ----
    for (int i = t; i < N_NODES; i += T) {
        float x = pos[i] + 0.5f * nsx[i];
        float y = pos[N_NODES + i] + 0.5f * nsy[i];
        cx[i] = x;
        cy[i] = y;
        // x,y >= 0 and < ~1026 -> cells 0..64, fits u8 each. *0.0625f exact (pow2).
        int cxi = (int)(x * 0.0625f);
        int cyi = (int)(y * 0.0625f);
        cell[i] = (unsigned short)(cxi | (cyi << 8));
        ex[i] = 0.f;
        ey[i] = 0.f;
    }
    grid_barrier(&bar[0]);

    // ---- Phase B: prefilter via 2 random u16 gathers/pair (service-rate bound) ----
    const int nq = E >> 2;      // quads of pairs; E divisible by 4
    for (int q = t; q < nq; q += T) {
        int base = q << 2;
        // streaming index loads: non-temporal so they don't evict the cell table
        int4v s4 = __builtin_nontemporal_load(reinterpret_cast<const int4v*>(src + base));
        int4v d4 = __builtin_nontemporal_load(reinterpret_cast<const int4v*>(dst + base));
        int ss[4] = {s4.x, s4.y, s4.z, s4.w};
        int dd[4] = {d4.x, d4.y, d4.z, d4.w};
        // issue all 8 cell gathers first (ILP), then evaluate
        int cs[4], cd[4];
#pragma unroll
        for (int k = 0; k < 4; ++k) { cs[k] = cell[ss[k]]; cd[k] = cell[dd[k]]; }
#pragma unroll
        for (int k = 0; k < 4; ++k) {
            int dxc = (cs[k] & 0xff) - (cd[k] & 0xff);
            int dyc = (cs[k] >> 8) - (cd[k] >> 8);
            // pass iff celldiff in {-1,0,1} for both dims (~0.1% of pairs)
            if ((unsigned)(dxc + 1) <= 2u && (unsigned)(dyc + 1) <= 2u) {
                int s = ss[k], d = dd[k];
                float dx = cx[s] - cx[d];
                float dy = cy[s] - cy[d];
                if (fabsf(dx) < THR && fabsf(dy) < THR) {
                    float inv = 0.5f / (dx * dx + dy * dy + 0.01f);
                    float fx = dx * inv;
                    float fy = dy * inv;
                    atomicAdd(&ex[s],  fx);
                    atomicAdd(&ex[d], -fx);
                    atomicAdd(&ey[s],  fy);
                    atomicAdd(&ey[d], -fy);
                }
            }
        }
    }
    grid_barrier(&bar[1]);

    // ---- Phase C: sum |ex| + |ey| (contiguous 2N floats starting at ex) ----
    float sum = 0.f;
    const int n4 = (2 * N_NODES) >> 2;
    const float4* v4 = reinterpret_cast<const float4*>(ex);
    for (int i = t; i < n4; i += T) {
        float4 a = v4[i];
        sum += fabsf(a.x) + fabsf(a.y) + fabsf(a.z) + fabsf(a.w);
    }
#pragma unroll
    for (int off = 32; off > 0; off >>= 1)
        sum += __shfl_down(sum, off, 64);
    __shared__ float ssm[4];
    int wid = threadIdx.x >> 6;
    if ((threadIdx.x & 63) == 0) ssm[wid] = sum;
    __syncthreads();
    if (threadIdx.x == 0)
        atomicAdd(out, ssm[0] + ssm[1] + ssm[2] + ssm[3]);
}

extern "C" void kernel_launch(void* const* d_in, const int* in_sizes, int n_in,
                              void* d_out, int out_size, void* d_ws, size_t ws_size,
                              hipStream_t stream) {
    const float* pos = (const float*)d_in[0];
    const float* nsx = (const float*)d_in[1];
    const float* nsy = (const float*)d_in[2];
    const int*   src = (const int*)d_in[3];
    const int*   dst = (const int*)d_in[4];
    float* out = (float*)d_out;
    int E = in_sizes[3];

    float* cx = (float*)d_ws;                       // [N] f32
    float* cy = cx + N_NODES;                       // [N]
    float* ex = cy + N_NODES;                       // [N]
    float* ey = ex + N_NODES;                       // [N]  (ex,ey contiguous)
    unsigned short* cell = (unsigned short*)(ey + N_NODES);  // [N] u16 = 2MB
    unsigned* bar = (unsigned*)(cell + N_NODES);    // [2] u32 barrier counters

    init_kernel<<<1, 1, 0, stream>>>(bar, out);

    fused_kernel<<<NBLK, NTHR, 0, stream>>>(
        pos, nsx, nsy, src, dst, cx, cy, cell, ex, ey, bar, out, E);
}

// Round 5
// 269.979 us; speedup vs baseline: 4.5707x; 2.4272x over previous
//
#include <hip/hip_runtime.h>

#define N_NODES 1048576
#define THR 16.0f
#define NBLK 1536   // 6 blocks/CU * 256 CU: co-resident by construction (cap is 8/CU)
#define NTHR 256
#define NXCD 8
#define STRIDE 32   // u32s per 128B cache line (keep hot atomics on separate lines)

typedef int int4v __attribute__((ext_vector_type(4)));

// Barrier slab layout (u32 indices; every counter/flag on its own 128B line):
//   arr[r]   at r*STRIDE        r=0..7  striped arrival counters (target NBLK/8 each)
//   claim[x] at 256 + x*STRIDE  x=0..7  per-XCD leader election
//   go[x]    at 512 + x*STRIDE  x=0..7  per-XCD release flag
//   wbdone   at 768                     count of XCDs whose L2 writeback completed
// slab = 1024 u32 = 4KB; two slabs (one per barrier use).

__global__ void init_kernel(unsigned* __restrict__ bar, float* __restrict__ out) {
    for (int k = threadIdx.x; k < 2048; k += 256) bar[k] = 0u;
    if (threadIdx.x == 0) out[0] = 0.f;   // d_out poisoned by harness; re-init every call
}

static __device__ __forceinline__ unsigned xcc_id() {
    unsigned x;
    asm("s_getreg_b32 %0, hwreg(HW_REG_XCC_ID)" : "=s"(x));
    return x & (NXCD - 1);
}

static __device__ __forceinline__ void poll_ge(unsigned* p, unsigned target) {
    while (__hip_atomic_load(p, __ATOMIC_RELAXED, __HIP_MEMORY_SCOPE_AGENT) < target)
        __builtin_amdgcn_s_sleep(2);
}

// Device-wide barrier with per-XCD (not per-block) cache maintenance.
// Rounds 3/4 lesson: buffer_wbl2/buffer_inv serialize at the L2 controllers;
// per-thread fencing = 1253us total, per-block = 655us. The HW-minimal count
// is per-XCD: buffer_wbl2 flushes the WHOLE issuing XCD's L2, so one per XCD
// (issued after every resident block drained its stores: each block's
// __syncthreads forces vmcnt(0) before its arrival-add) covers everything.
// One buffer_inv per XCD (inv_after, barrier 2 only) before re-reading lines
// whose authoritative value moved to IF (memory-side atomics on ex/ey while
// stale phase-A zero-lines sit valid in L2). L1 is write-through no-allocate,
// so no CU L1 ever holds a stale copy of these store-then-reload arrays.
static __device__ void xcd_barrier(unsigned* slab, bool inv_after) {
    __syncthreads();   // all waves' stores drained to this XCD's L2
    if (threadIdx.x == 0) {
        unsigned* arr    = slab;
        unsigned* claim  = slab + 256;
        unsigned* go     = slab + 512;
        unsigned* wbdone = slab + 768;
        const unsigned r = blockIdx.x & 7u;
        __hip_atomic_fetch_add(&arr[r * STRIDE], 1u, __ATOMIC_RELAXED, __HIP_MEMORY_SCOPE_AGENT);
        for (unsigned k = 0; k < 8; ++k)            // all blocks arrived =>
            poll_ge(&arr[k * STRIDE], NBLK / 8);    // all stores are in some XCD L2
        const unsigned x = xcc_id();
        if (__hip_atomic_exchange(&claim[x * STRIDE], 1u,
                                  __ATOMIC_RELAXED, __HIP_MEMORY_SCOPE_AGENT) == 0u) {
            // XCD leader: one writeback of this XCD's L2 to the coherence point
            __builtin_amdgcn_fence(__ATOMIC_RELEASE, "agent");     // waitcnt + buffer_wbl2
            __hip_atomic_fetch_add(wbdone, 1u, __ATOMIC_RELEASE, __HIP_MEMORY_SCOPE_AGENT);
            poll_ge(wbdone, NXCD);                                 // all 8 L2s flushed
            if (inv_after)
                __builtin_amdgcn_fence(__ATOMIC_ACQUIRE, "agent"); // one buffer_inv
            __hip_atomic_store(&go[x * STRIDE], 1u, __ATOMIC_RELAXED, __HIP_MEMORY_SCOPE_AGENT);
        } else {
            poll_ge(&go[x * STRIDE], 1u);   // released only after local leader's inv
        }
    }
    __syncthreads();
}

// cells of width 16: |dx| < 16 is impossible when |cellx_s - cellx_d| >= 2,
// because cx in cell c means cx in [16c, 16c+16), so celldiff k>=2 implies
// |dx| > 16(k-1) >= 16. Prefilter is exactly conservative (no false rejects)
// since cells are computed from the SAME stored cx/cy the exact path gathers.
__global__ __launch_bounds__(NTHR, 6)
void fused_kernel(const float* __restrict__ pos,
                  const float* __restrict__ nsx,
                  const float* __restrict__ nsy,
                  const int* __restrict__ src,
                  const int* __restrict__ dst,
                  float* __restrict__ cx, float* __restrict__ cy,
                  unsigned short* __restrict__ cell,
                  float* __restrict__ ex, float* __restrict__ ey,
                  unsigned* __restrict__ bar,
                  float* __restrict__ out, int E) {
    const int t = blockIdx.x * NTHR + threadIdx.x;
    const int T = NBLK * NTHR;

    // ---- Phase A: node centers, cell codes, zero force accumulators ----
    for (int i = t; i < N_NODES; i += T) {
        float x = pos[i] + 0.5f * nsx[i];
        float y = pos[N_NODES + i] + 0.5f * nsy[i];
        cx[i] = x;
        cy[i] = y;
        // x,y >= 0 and < ~1026 -> cells 0..64, fits u8 each. *0.0625f exact (pow2).
        int cxi = (int)(x * 0.0625f);
        int cyi = (int)(y * 0.0625f);
        cell[i] = (unsigned short)(cxi | (cyi << 8));
        ex[i] = 0.f;
        ey[i] = 0.f;
    }
    xcd_barrier(bar, /*inv_after=*/false);   // wbl2 only: nothing stale to inv

    // ---- Phase B: prefilter via 2 random u16 gathers/pair (service-rate bound) ----
    const int nq = E >> 2;      // quads of pairs; E divisible by 4
    for (int q = t; q < nq; q += T) {
        int base = q << 2;
        // streaming index loads: non-temporal so they don't evict the cell table
        int4v s4 = __builtin_nontemporal_load(reinterpret_cast<const int4v*>(src + base));
        int4v d4 = __builtin_nontemporal_load(reinterpret_cast<const int4v*>(dst + base));
        int ss[4] = {s4.x, s4.y, s4.z, s4.w};
        int dd[4] = {d4.x, d4.y, d4.z, d4.w};
        // issue all 8 cell gathers first (ILP), then evaluate
        int cs[4], cd[4];
#pragma unroll
        for (int k = 0; k < 4; ++k) { cs[k] = cell[ss[k]]; cd[k] = cell[dd[k]]; }
#pragma unroll
        for (int k = 0; k < 4; ++k) {
            int dxc = (cs[k] & 0xff) - (cd[k] & 0xff);
            int dyc = (cs[k] >> 8) - (cd[k] >> 8);
            // pass iff celldiff in {-1,0,1} for both dims (~0.1% of pairs)
            if ((unsigned)(dxc + 1) <= 2u && (unsigned)(dyc + 1) <= 2u) {
                int s = ss[k], d = dd[k];
                float dx = cx[s] - cx[d];
                float dy = cy[s] - cy[d];
                if (fabsf(dx) < THR && fabsf(dy) < THR) {
                    float inv = 0.5f / (dx * dx + dy * dy + 0.01f);
                    float fx = dx * inv;
                    float fy = dy * inv;
                    atomicAdd(&ex[s],  fx);
                    atomicAdd(&ex[d], -fx);
                    atomicAdd(&ey[s],  fy);
                    atomicAdd(&ey[d], -fy);
                }
            }
        }
    }
    xcd_barrier(bar + 1024, /*inv_after=*/true);  // inv: drop stale zero ex/ey L2 lines

    // ---- Phase C: sum |ex| + |ey| (contiguous 2N floats starting at ex) ----
    float sum = 0.f;
    const int n4 = (2 * N_NODES) >> 2;
    const float4* v4 = reinterpret_cast<const float4*>(ex);
    for (int i = t; i < n4; i += T) {
        float4 a = v4[i];
        sum += fabsf(a.x) + fabsf(a.y) + fabsf(a.z) + fabsf(a.w);
    }
#pragma unroll
    for (int off = 32; off > 0; off >>= 1)
        sum += __shfl_down(sum, off, 64);
    __shared__ float ssm[4];
    int wid = threadIdx.x >> 6;
    if ((threadIdx.x & 63) == 0) ssm[wid] = sum;
    __syncthreads();
    if (threadIdx.x == 0)
        atomicAdd(out, ssm[0] + ssm[1] + ssm[2] + ssm[3]);
}

extern "C" void kernel_launch(void* const* d_in, const int* in_sizes, int n_in,
                              void* d_out, int out_size, void* d_ws, size_t ws_size,
                              hipStream_t stream) {
    const float* pos = (const float*)d_in[0];
    const float* nsx = (const float*)d_in[1];
    const float* nsy = (const float*)d_in[2];
    const int*   src = (const int*)d_in[3];
    const int*   dst = (const int*)d_in[4];
    float* out = (float*)d_out;
    int E = in_sizes[3];

    float* cx = (float*)d_ws;                       // [N] f32
    float* cy = cx + N_NODES;                       // [N]
    float* ex = cy + N_NODES;                       // [N]
    float* ey = ex + N_NODES;                       // [N]  (ex,ey contiguous)
    unsigned short* cell = (unsigned short*)(ey + N_NODES);  // [N] u16 = 2MB
    unsigned* bar = (unsigned*)(cell + N_NODES);    // 2 barrier slabs, 2048 u32 = 8KB

    init_kernel<<<1, 256, 0, stream>>>(bar, out);

    fused_kernel<<<NBLK, NTHR, 0, stream>>>(
        pos, nsx, nsy, src, dst, cx, cy, cell, ex, ey, bar, out, E);
}

// Round 7
// 186.339 us; speedup vs baseline: 6.6223x; 1.4489x over previous
//
#include <hip/hip_runtime.h>

#define N_NODES 1048576
#define THR 16.0f

typedef int int4v __attribute__((ext_vector_type(4)));
typedef float float4v __attribute__((ext_vector_type(4)));

// cells of width 16: |dx| < 16 is impossible when |cellx_s - cellx_d| >= 2,
// because cx in cell c means cx in [16c, 16c+16), so celldiff k>=2 implies
// |dx| > 16(k-1) >= 16. Prefilter is exactly conservative (no false rejects)
// since cells are computed from the SAME stored cxy the exact path gathers.
//
// 4 nodes/thread, fully vectorized: float4 in (pos x, pos y, nsx, nsy),
// 2x float4 out (interleaved cxy), ushort4 cell codes, float4 NT zeros.
__global__ void centers_kernel(const float* __restrict__ pos,
                               const float* __restrict__ nsx,
                               const float* __restrict__ nsy,
                               float* __restrict__ cxy,      // [2N] interleaved {cx,cy}
                               unsigned short* __restrict__ cell,
                               float* __restrict__ ex, float* __restrict__ ey,
                               float* __restrict__ out) {
    int t = blockIdx.x * blockDim.x + threadIdx.x;
    int base = t * 4;
    if (base < N_NODES) {
        float4 px = *reinterpret_cast<const float4*>(pos + base);
        float4 py = *reinterpret_cast<const float4*>(pos + N_NODES + base);
        float4 sx = *reinterpret_cast<const float4*>(nsx + base);
        float4 sy = *reinterpret_cast<const float4*>(nsy + base);
        float cx0 = px.x + 0.5f * sx.x, cy0 = py.x + 0.5f * sy.x;
        float cx1 = px.y + 0.5f * sx.y, cy1 = py.y + 0.5f * sy.y;
        float cx2 = px.z + 0.5f * sx.z, cy2 = py.z + 0.5f * sy.z;
        float cx3 = px.w + 0.5f * sx.w, cy3 = py.w + 0.5f * sy.w;
        // interleaved centers: one 8B gather per endpoint on the exact path
        float4 c01 = {cx0, cy0, cx1, cy1};
        float4 c23 = {cx2, cy2, cx3, cy3};
        *reinterpret_cast<float4*>(cxy + 2 * base)     = c01;
        *reinterpret_cast<float4*>(cxy + 2 * base + 4) = c23;
        // x,y >= 0 and < ~1026 -> cells 0..64, fits u8 each. *0.0625f exact (pow2).
        ushort4 cc;
        cc.x = (unsigned short)(((int)(cx0 * 0.0625f)) | (((int)(cy0 * 0.0625f)) << 8));
        cc.y = (unsigned short)(((int)(cx1 * 0.0625f)) | (((int)(cy1 * 0.0625f)) << 8));
        cc.z = (unsigned short)(((int)(cx2 * 0.0625f)) | (((int)(cy2 * 0.0625f)) << 8));
        cc.w = (unsigned short)(((int)(cx3 * 0.0625f)) | (((int)(cy3 * 0.0625f)) << 8));
        *reinterpret_cast<ushort4*>(cell + base) = cc;
        // zero accumulators; NT: these lines are next touched by memory-side atomics
        float4v z = {0.f, 0.f, 0.f, 0.f};
        __builtin_nontemporal_store(z, reinterpret_cast<float4v*>(ex + base));
        __builtin_nontemporal_store(z, reinterpret_cast<float4v*>(ey + base));
    }
    if (t == 0) out[0] = 0.f;   // d_out poisoned by harness; re-init every call
}

__global__ void pairs_kernel(const int* __restrict__ src,
                             const int* __restrict__ dst,
                             const unsigned short* __restrict__ cell,
                             const float* __restrict__ cxy,   // interleaved {cx,cy}
                             float* __restrict__ ex, float* __restrict__ ey,
                             int E) {
    int t = blockIdx.x * blockDim.x + threadIdx.x;
    int base = t * 4;
    if (base >= E) return;
    // streaming index loads: non-temporal so they don't evict the 2MB cell table from L2
    int4v s4 = __builtin_nontemporal_load(reinterpret_cast<const int4v*>(src + base));
    int4v d4 = __builtin_nontemporal_load(reinterpret_cast<const int4v*>(dst + base));
    int ss[4] = {s4.x, s4.y, s4.z, s4.w};
    int dd[4] = {d4.x, d4.y, d4.z, d4.w};
    // issue all 8 cell gathers first (ILP), then evaluate
    int cs[4], cd[4];
#pragma unroll
    for (int k = 0; k < 4; ++k) { cs[k] = cell[ss[k]]; cd[k] = cell[dd[k]]; }
    const float2* c2 = reinterpret_cast<const float2*>(cxy);
#pragma unroll
    for (int k = 0; k < 4; ++k) {
        int dxc = (cs[k] & 0xff) - (cd[k] & 0xff);
        int dyc = (cs[k] >> 8) - (cd[k] >> 8);
        // pass iff celldiff in {-1,0,1} for both dims (~0.2% of pairs)
        if ((unsigned)(dxc + 1) <= 2u && (unsigned)(dyc + 1) <= 2u) {
            int s = ss[k], d = dd[k];
            float2 ps = c2[s];
            float2 pd = c2[d];
            float dx = ps.x - pd.x;
            float dy = ps.y - pd.y;
            if (fabsf(dx) < THR && fabsf(dy) < THR) {
                float inv = 0.5f / (dx * dx + dy * dy + 0.01f);
                float fx = dx * inv;
                float fy = dy * inv;
                atomicAdd(&ex[s],  fx);
                atomicAdd(&ex[d], -fx);
                atomicAdd(&ey[s],  fy);
                atomicAdd(&ey[d], -fy);
            }
        }
    }
}

__global__ void reduce_kernel(const float* __restrict__ v,  // ex then ey, contiguous 2N
                              float* __restrict__ out, int n4) {
    int t = blockIdx.x * blockDim.x + threadIdx.x;
    int stride = gridDim.x * blockDim.x;
    float sum = 0.f;
    for (int i = t; i < n4; i += stride) {
        float4 a = reinterpret_cast<const float4*>(v)[i];
        sum += fabsf(a.x) + fabsf(a.y) + fabsf(a.z) + fabsf(a.w);
    }
#pragma unroll
    for (int off = 32; off > 0; off >>= 1)
        sum += __shfl_down(sum, off, 64);
    __shared__ float ss[4];
    int wid = threadIdx.x >> 6;
    if ((threadIdx.x & 63) == 0) ss[wid] = sum;
    __syncthreads();
    if (threadIdx.x == 0)
        atomicAdd(out, ss[0] + ss[1] + ss[2] + ss[3]);
}

extern "C" void kernel_launch(void* const* d_in, const int* in_sizes, int n_in,
                              void* d_out, int out_size, void* d_ws, size_t ws_size,
                              hipStream_t stream) {
    const float* pos = (const float*)d_in[0];
    const float* nsx = (const float*)d_in[1];
    const float* nsy = (const float*)d_in[2];
    const int*   src = (const int*)d_in[3];
    const int*   dst = (const int*)d_in[4];
    float* out = (float*)d_out;
    const int E = in_sizes[3];

    float* cxy = (float*)d_ws;                      // [2N] f32 interleaved {cx,cy}
    float* ex  = cxy + 2 * N_NODES;                 // [N]
    float* ey  = ex + N_NODES;                      // [N]  (ex,ey contiguous for reduce)
    unsigned short* cell = (unsigned short*)(ey + N_NODES);  // [N] u16 = 2MB

    // 4 nodes per thread
    centers_kernel<<<N_NODES / (256 * 4), 256, 0, stream>>>(
        pos, nsx, nsy, cxy, cell, ex, ey, out);

    int nt = E / 4;   // E = 16777216
    pairs_kernel<<<(nt + 255) / 256, 256, 0, stream>>>(
        src, dst, cell, cxy, ex, ey, E);

    int n4 = (2 * N_NODES) / 4;
    reduce_kernel<<<2048, 256, 0, stream>>>(ex, out, n4);
}